// Round 17
// baseline (10842.178 us; speedup 1.0000x reference)
//
#include <hip/hip_runtime.h>

#define TT   128
#define FF   64
#define HH   512
#define GG   2048    // 4H
#define K1   576
#define K2   1024
#define KB1  72      // K1/8
#define KB2  128     // K2/8
#define NBLK 256
#define QS   520     // Q row stride in halves (1040B, 16B-aligned)

using f16x8 = __attribute__((ext_vector_type(8))) _Float16;
using f16x4 = __attribute__((ext_vector_type(4))) _Float16;
using f16x2 = __attribute__((ext_vector_type(2))) _Float16;
using f32x4 = __attribute__((ext_vector_type(4))) float;

// ---------------------------------------------------------------------------
// Coalesced repack (validated r9-r14): block kb stages 8 rows of [U;W] into
// LDS, writes dest-linear 16B chunks. Layout: element (ct,kb,c,j) at
// ((ct*K8+kb)*16+c)*8+j holds B[k=kb*8+j][col], col=(c&3)*512+ct*4+(c>>2).
// ---------------------------------------------------------------------------
__global__ void pack_weights(const float* __restrict__ U, const float* __restrict__ W,
                             const float* __restrict__ bias, int K8, int Kh,
                             _Float16* __restrict__ Bp, float* __restrict__ pb)
{
    __shared__ _Float16 T[8][GG];
    const int kb = blockIdx.x;
    const int tid = threadIdx.x;
    for (int i = tid; i < 8 * (GG / 4); i += 256) {
        int r = i / (GG / 4), c4 = (i % (GG / 4)) * 4;
        int k = kb * 8 + r;
        const float* src = (k < Kh) ? (U + (size_t)k * GG) : (W + (size_t)(k - Kh) * GG);
        float4 v = *(const float4*)(src + c4);
        T[r][c4 + 0] = (_Float16)v.x; T[r][c4 + 1] = (_Float16)v.y;
        T[r][c4 + 2] = (_Float16)v.z; T[r][c4 + 3] = (_Float16)v.w;
    }
    __syncthreads();
    for (int m = tid; m < 2048; m += 256) {
        int ct = m >> 4, c = m & 15;
        int col = (c & 3) * HH + ct * 4 + (c >> 2);
        f16x8 v;
#pragma unroll
        for (int j = 0; j < 8; ++j) v[j] = T[j][col];
        *(f16x8*)(Bp + (((size_t)ct * K8 + kb) * 16 + c) * 8) = v;
    }
    if (kb == 0)
        for (int p = tid; p < GG; p += 256) {
            int ct = p >> 4, c = p & 15;
            pb[p] = bias[(c & 3) * HH + ct * 4 + (c >> 2)];
        }
}

// DPP quad_perm broadcast (VALU). Validated r3-r14.
template <int CTRL>
__device__ __forceinline__ float qbcast(float v) {
    return __int_as_float(__builtin_amdgcn_mov_dpp(__float_as_int(v), CTRL, 0xF, 0xF, true));
}

// async global->LDS DMA, 16B/lane, sc0 (L1-bypass). Validated r9+.
__device__ __forceinline__ void gld_lds16_sc0(const _Float16* g, _Float16* l) {
    __builtin_amdgcn_global_load_lds(
        (__attribute__((address_space(1))) const void*)g,
        (__attribute__((address_space(3))) void*)l, 16, 0, 1);
}

// ---------------------------------------------------------------------------
// Gate epilogue (r17): single-activation + DPP quad-broadcast (validated
// r10-r14), with cell state in REGISTERS (csr[4], statically indexed by the
// unrolled j loop) instead of LDS: removes a ~120cy ds_read + ds_write from
// the serial gate chain per j per layer. Non-gsel0 lanes carry garbage csr
// (bounded: fg<1 contraction) that is never read. Math order identical to
// r11 -> absmax must be bit-identical.
// ---------------------------------------------------------------------------
__device__ __forceinline__ void lstm_epi(
    f32x4 v4, float bias, float (&csr)[4], _Float16* __restrict__ hstp,
    int kq, int c, int ubase)
{
    const int gsel = c & 3;
    const int ub = ubase + (c >> 2);
#pragma unroll
    for (int j = 0; j < 4; ++j) {
        float v = v4[j] + bias;
        float sig = 1.f / (1.f + __expf(-v));
        float act = (gsel == 2) ? (v > 0.f ? v : 0.f) : sig;
        float ig  = qbcast<0x00>(act);
        float fg  = qbcast<0x55>(act);
        float cin = qbcast<0xAA>(act);
        float og  = qbcast<0xFF>(act);
        float cp = csr[j];
        float cn = fg * cp + ig * cin;
        float hn = og * (cn > 0.f ? cn : 0.f);
        csr[j] = cn;
        if (gsel == 0)
            hstp[(kq * 4 + j) * 40 + ub] = (_Float16)hn;
    }
}

#define MFMA16(av, bv, acc) \
    acc = __builtin_amdgcn_mfma_f32_16x16x32_f16(av, bv, acc, 0, 0, 0)

// ---------------------------------------------------------------------------
// Persistent 2-layer LSTM — r17 = EXACT r11 structure (best known-good,
// 4555us; fusion of r15/r16 abandoned — it correlates 2/2 with correctness
// failures, mechanism unidentified) + two conservative changes:
//  (1) cell state in registers (csr1/csr2[8][4], 64 VGPRs, static indexing)
//  (2) mapping-robust barrier: release fence -> relaxed add -> relaxed spin
//      -> acquire fence (r16 semantics; removes the latent XCD-mapping
//      assumption from the known-good base).
// c1s/c2s remain declared+zeroed ONLY as LDS ballast (keeps LDS>80KB ->
// exactly 1 block/CU, preserving the XCD-local dispatch pattern).
// 256 blocks x 512 threads (8 waves, 2/SIMD); wave w owns one 16-col tile of
// both layers, full K, 200 AGPR-pinned weight regs; 9 pipelined regions per
// superstep, 1 barrier each; sc0 DMA; XCD-local rg mapping.
// ---------------------------------------------------------------------------
__global__ __launch_bounds__(512, 2) void lstm_persist(
    const float* __restrict__ x,
    const _Float16* __restrict__ Bp1, const float* __restrict__ pb1,
    const _Float16* __restrict__ Bp2, const float* __restrict__ pb2,
    const float* __restrict__ Wd, const float* __restrict__ bd,
    _Float16* __restrict__ h1b,   // [2][2048][512]
    _Float16* __restrict__ h2b,   // [2][2048][512]
    unsigned* __restrict__ bar,   // [16][32] rowgroup counters
    float* __restrict__ out)
{
    __shared__ _Float16 Q1[2][16 * QS];     // 32.5KB h1 chunks
    __shared__ _Float16 Q2[2][16 * QS];     // 32.5KB h2 chunks
    __shared__ _Float16 Xp[2][16][72];      // 4.5KB  x_t fp16
    __shared__ float    c1s[128 * 33];      // 16.5KB LDS ballast (keeps 1 blk/CU)
    __shared__ float    c2s[128 * 33];      // 16.5KB LDS ballast
    __shared__ _Float16 hst[2][2][16][40];  // 5KB   [parity][layer][row][unit]

    const int tid = threadIdx.x;
    const int w = tid >> 6, lane = tid & 63;
    const int b = blockIdx.x;
    const int rg = 2 * (b & 7) + ((b >> 3) & 1);   // XCD-local rowgroup
    const int cg = b >> 4;
    const int r0 = rg * 128;
    const int c = lane & 15, kq = lane >> 4;

    for (int i = tid; i < 128 * 33; i += 512) { c1s[i] = 0.f; c2s[i] = 0.f; }
    for (int i = tid; i < 2 * 2 * 16 * 40; i += 512) (&hst[0][0][0][0])[i] = (_Float16)0.f;

    // ---- one-time: ALL weights -> AGPRs (200 regs/lane, "+a" pinned) ----
    const int ct = cg * 8 + w;
    f16x8 w1f[18], w2f[32];
#pragma unroll
    for (int kc = 0; kc < 18; ++kc)
        w1f[kc] = *(const f16x8*)(Bp1 + (((size_t)ct * KB1 + kc * 4 + kq) * 16 + c) * 8);
#pragma unroll
    for (int kc = 0; kc < 32; ++kc)
        w2f[kc] = *(const f16x8*)(Bp2 + (((size_t)ct * KB2 + kc * 4 + kq) * 16 + c) * 8);
#pragma unroll
    for (int kc = 0; kc < 18; ++kc) asm volatile("" : "+a"(w1f[kc]));
#pragma unroll
    for (int kc = 0; kc < 32; ++kc) asm volatile("" : "+a"(w2f[kc]));

    const float bias1 = pb1[ct * 16 + c];
    const float bias2 = pb2[ct * 16 + c];
    const int ub0 = w * 4;
    const int xrow = tid >> 5, xc2 = (tid & 31) * 2;

    // ---- r17: per-thread cell state, statically indexed (rule #20 safe:
    // the ch loop is fully unrolled). 64 VGPRs.
    float csr1[8][4], csr2[8][4];
#pragma unroll
    for (int i = 0; i < 8; ++i)
#pragma unroll
        for (int j = 0; j < 4; ++j) { csr1[i][j] = 0.f; csr2[i][j] = 0.f; }

    for (int s = 0; s <= TT; ++s) {
        const int pr1 = (s + 1) & 1, pw1 = s & 1;
        const int pr2 = s & 1,       pw2 = (s + 1) & 1;
        const _Float16* h1r = h1b + (size_t)pr1 * 2048 * HH;
        const _Float16* h2r = h2b + (size_t)pr2 * 2048 * HH;
        _Float16* h1w = h1b + (size_t)pw1 * 2048 * HH;
        _Float16* h2w = h2b + (size_t)pw2 * 2048 * HH;
        const bool doL1 = (s < TT);
        const bool doL2 = (s >= 1);

        // ---- prologue: stage chunk 0 (DMA sc0) + x(0) ----
        {
#pragma unroll
            for (int i = 0; i < 2; ++i) {
                int r = w * 2 + i;
                gld_lds16_sc0(h1r + (size_t)(r0 + r) * HH + lane * 8, &Q1[0][r * QS]);
                gld_lds16_sc0(h2r + (size_t)(r0 + r) * HH + lane * 8, &Q2[0][r * QS]);
            }
            if (doL1) {
                float2 xv = *(const float2*)(x + ((size_t)(r0 + xrow) * TT + s) * FF + xc2);
                *(f16x2*)&Xp[0][xrow][xc2] = (f16x2){(_Float16)xv.x, (_Float16)xv.y};
            }
        }
        __syncthreads();

        // ---- pipelined regions: 1 barrier each ----
#pragma unroll
        for (int ch = 0; ch <= 8; ++ch) {
            const int par = ch & 1;

            // (1) DMA prefetch chunk ch+1 -> Q[par^1]
            if (ch <= 6) {
                const int gr = r0 + (ch + 1) * 16;
#pragma unroll
                for (int i = 0; i < 2; ++i) {
                    int r = w * 2 + i;
                    gld_lds16_sc0(h1r + (size_t)(gr + r) * HH + lane * 8, &Q1[par ^ 1][r * QS]);
                    gld_lds16_sc0(h2r + (size_t)(gr + r) * HH + lane * 8, &Q2[par ^ 1][r * QS]);
                }
            }
            float2 xnext{0.f, 0.f};
            const bool havex = (ch <= 6) && doL1;
            if (havex)
                xnext = *(const float2*)(x +
                    ((size_t)(r0 + (ch + 1) * 16 + xrow) * TT + s) * FF + xc2);

            // (2) hstore chunk ch-1 from hst[par^1] (256 threads, f16x4)
            if (ch >= 1 && tid < 256) {
                int layer = tid >> 7, r = (tid >> 3) & 15, cq = tid & 7;
                f16x4 hv = *(const f16x4*)&hst[par ^ 1][layer][r][cq * 4];
                _Float16* dst = (layer ? h2w : h1w)
                    + (size_t)(r0 + (ch - 1) * 16 + r) * HH + cg * 32 + cq * 4;
                *(f16x4*)dst = hv;
            }

            // (3) MFMA + epilogue for chunk ch (EXACT r11 structure)
            if (ch <= 7) {
                const char* q1b = (const char*)&Q1[par][0] + c * (QS * 2);
                const char* q2b = (const char*)&Q2[par][0] + c * (QS * 2);
                if (doL1) {   // ---- L1: [h1 | x] @ [U1;W1], 2 acc chains ----
                    f32x4 a0{0.f, 0.f, 0.f, 0.f}, a1 = a0;
#pragma unroll
                    for (int kc = 0; kc < 8; ++kc) {
                        f16x8 av = *(const f16x8*)(q1b + kc * 64 + kq * 16);
                        MFMA16(av, w1f[kc], a0);
                    }
#pragma unroll
                    for (int kc = 8; kc < 16; ++kc) {
                        f16x8 av = *(const f16x8*)(q1b + kc * 64 + kq * 16);
                        MFMA16(av, w1f[kc], a1);
                    }
                    {
                        f16x8 av = *(const f16x8*)&Xp[par][c][kq * 8];
                        MFMA16(av, w1f[16], a0);
                        av = *(const f16x8*)&Xp[par][c][32 + kq * 8];
                        MFMA16(av, w1f[17], a1);
                    }
                    lstm_epi(a0 + a1, bias1, csr1[ch], &hst[par][0][0][0], kq, c, ub0);
                }
                if (doL2) {   // ---- L2: [h2 | h1] @ [U2;W2], 2 acc chains ----
                    f32x4 b0{0.f, 0.f, 0.f, 0.f}, b1 = b0;
#pragma unroll
                    for (int kc = 0; kc < 16; ++kc) {
                        f16x8 av = *(const f16x8*)(q2b + kc * 64 + kq * 16);
                        MFMA16(av, w2f[kc], b0);
                    }
#pragma unroll
                    for (int kc = 0; kc < 16; ++kc) {
                        f16x8 av = *(const f16x8*)(q1b + kc * 64 + kq * 16);
                        MFMA16(av, w2f[16 + kc], b1);
                    }
                    lstm_epi(b0 + b1, bias2, csr2[ch], &hst[par][1][0][0], kq, c, ub0);
                }
            }

            // (4) x(ch+1) -> Xp[par^1]
            if (havex)
                *(f16x2*)&Xp[par ^ 1][xrow][xc2] =
                    (f16x2){(_Float16)xnext.x, (_Float16)xnext.y};

            __syncthreads();   // single barrier per region
        }

        // ---- rowgroup barrier: release fence -> relaxed add/spin -> acquire
        // fence (mapping-robust; relaxed polls avoid the r2 buffer_inv storm).
        if (tid == 0) {
            __threadfence();   // release: wbl2 pushes this XCD's h-lines to L3
            __hip_atomic_fetch_add(&bar[rg * 32], 1u,
                                   __ATOMIC_RELAXED, __HIP_MEMORY_SCOPE_AGENT);
            const unsigned target = 16u * (unsigned)(s + 1);
            while (__hip_atomic_load(&bar[rg * 32],
                                     __ATOMIC_RELAXED, __HIP_MEMORY_SCOPE_AGENT) < target)
                __builtin_amdgcn_s_sleep(2);
            __threadfence();   // acquire: inv drops stale L2 lines before next DMA
        }
        __syncthreads();
    }

    // ---- dense head: out = h2_127 @ Wd + bd (cg==0 blocks; 4 threads/row) ----
    if (cg == 0) {
        const _Float16* hf = h2b + (size_t)((TT + 1) & 1) * 2048 * HH;
        int row = tid >> 2, part = tid & 3;
        const _Float16* hr = hf + (size_t)(r0 + row) * HH + part * 128;
        const float* wd = Wd + part * 128;
        float ssum = 0.f;
#pragma unroll
        for (int u8 = 0; u8 < 16; ++u8) {
            f16x8 hv = *(const f16x8*)(hr + u8 * 8);
#pragma unroll
            for (int k = 0; k < 8; ++k) ssum += (float)hv[k] * wd[u8 * 8 + k];
        }
        ssum += __shfl_xor(ssum, 1);
        ssum += __shfl_xor(ssum, 2);
        if (part == 0) out[r0 + row] = ssum + bd[0];
    }
}

extern "C" void kernel_launch(void* const* d_in, const int* in_sizes, int n_in,
                              void* d_out, int out_size, void* d_ws, size_t ws_size,
                              hipStream_t stream)
{
    const float* x  = (const float*)d_in[0];
    const float* W1 = (const float*)d_in[1];
    const float* U1 = (const float*)d_in[2];
    const float* b1 = (const float*)d_in[3];
    const float* W2 = (const float*)d_in[4];
    const float* U2 = (const float*)d_in[5];
    const float* b2 = (const float*)d_in[6];
    const float* Wd = (const float*)d_in[7];
    const float* bd = (const float*)d_in[8];
    float* out = (float*)d_out;

    char* ws = (char*)d_ws;
    size_t off = 0;
    _Float16* Bp1 = (_Float16*)(ws + off); off += (size_t)K1 * GG * 2;
    _Float16* Bp2 = (_Float16*)(ws + off); off += (size_t)K2 * GG * 2;
    float*    pb1 = (float*)(ws + off);    off += (size_t)GG * 4;
    float*    pb2 = (float*)(ws + off);    off += (size_t)GG * 4;
    _Float16* h1b = (_Float16*)(ws + off); off += (size_t)2 * 2048 * HH * 2;
    _Float16* h2b = (_Float16*)(ws + off); off += (size_t)2 * 2048 * HH * 2;
    unsigned* bar = (unsigned*)(ws + off); off += 16 * 32 * 4;

    hipMemsetAsync(h1b, 0, (size_t)2 * 2048 * HH * 2, stream);
    hipMemsetAsync(h2b, 0, (size_t)2 * 2048 * HH * 2, stream);
    hipMemsetAsync(bar, 0, 16 * 32 * 4, stream);

    pack_weights<<<KB1, 256, 0, stream>>>(U1, W1, b1, KB1, HH, Bp1, pb1);
    pack_weights<<<KB2, 256, 0, stream>>>(U2, W2, b2, KB2, HH, Bp2, pb2);
    lstm_persist<<<NBLK, 512, 0, stream>>>(x, Bp1, pb1, Bp2, pb2, Wd, bd,
                                           h1b, h2b, bar, out);
}

// Round 18
// 8526.031 us; speedup vs baseline: 1.2717x; 1.2717x over previous
//
#include <hip/hip_runtime.h>

#define TT   128
#define FF   64
#define HH   512
#define GG   2048    // 4H
#define K1   576
#define K2   1024
#define KB1  72      // K1/8
#define KB2  128     // K2/8
#define NBLK 256
#define QS   520     // Q row stride in halves (1040B, 16B-aligned)

using f16x8 = __attribute__((ext_vector_type(8))) _Float16;
using f16x4 = __attribute__((ext_vector_type(4))) _Float16;
using f16x2 = __attribute__((ext_vector_type(2))) _Float16;
using f32x4 = __attribute__((ext_vector_type(4))) float;

// ---------------------------------------------------------------------------
// Coalesced repack (validated r9-r17): block kb stages 8 rows of [U;W] into
// LDS, writes dest-linear 16B chunks. Layout: element (ct,kb,c,j) at
// ((ct*K8+kb)*16+c)*8+j holds B[k=kb*8+j][col], col=(c&3)*512+ct*4+(c>>2).
// ---------------------------------------------------------------------------
__global__ void pack_weights(const float* __restrict__ U, const float* __restrict__ W,
                             const float* __restrict__ bias, int K8, int Kh,
                             _Float16* __restrict__ Bp, float* __restrict__ pb)
{
    __shared__ _Float16 T[8][GG];
    const int kb = blockIdx.x;
    const int tid = threadIdx.x;
    for (int i = tid; i < 8 * (GG / 4); i += 256) {
        int r = i / (GG / 4), c4 = (i % (GG / 4)) * 4;
        int k = kb * 8 + r;
        const float* src = (k < Kh) ? (U + (size_t)k * GG) : (W + (size_t)(k - Kh) * GG);
        float4 v = *(const float4*)(src + c4);
        T[r][c4 + 0] = (_Float16)v.x; T[r][c4 + 1] = (_Float16)v.y;
        T[r][c4 + 2] = (_Float16)v.z; T[r][c4 + 3] = (_Float16)v.w;
    }
    __syncthreads();
    for (int m = tid; m < 2048; m += 256) {
        int ct = m >> 4, c = m & 15;
        int col = (c & 3) * HH + ct * 4 + (c >> 2);
        f16x8 v;
#pragma unroll
        for (int j = 0; j < 8; ++j) v[j] = T[j][col];
        *(f16x8*)(Bp + (((size_t)ct * K8 + kb) * 16 + c) * 8) = v;
    }
    if (kb == 0)
        for (int p = tid; p < GG; p += 256) {
            int ct = p >> 4, c = p & 15;
            pb[p] = bias[(c & 3) * HH + ct * 4 + (c >> 2)];
        }
}

// DPP quad_perm broadcast (VALU). Validated r3-r17.
template <int CTRL>
__device__ __forceinline__ float qbcast(float v) {
    return __int_as_float(__builtin_amdgcn_mov_dpp(__float_as_int(v), CTRL, 0xF, 0xF, true));
}

// async global->LDS DMA, 16B/lane, sc0 (L1-bypass). Validated r9+.
__device__ __forceinline__ void gld_lds16_sc0(const _Float16* g, _Float16* l) {
    __builtin_amdgcn_global_load_lds(
        (__attribute__((address_space(1))) const void*)g,
        (__attribute__((address_space(3))) void*)l, 16, 0, 1);
}

// ---------------------------------------------------------------------------
// Gate epilogue — EXACT r11 form (validated fast+correct): single-activation
// + DPP quad-broadcast; cell state in LDS, stride 33 (conflict-free).
// C/D 16x16: col=lane&15, row=kq*4+j. hst stride 40.
// (r17 lesson: cs-in-registers exceeds the ~128-VGPR RA budget -> scratch
// spill, 2.4x slowdown. LDS cs is the right home.)
// ---------------------------------------------------------------------------
__device__ __forceinline__ void lstm_epi(
    f32x4 v4, float bias, float* __restrict__ cs, _Float16* __restrict__ hstp,
    int R0, int kq, int c, int ubase)
{
    const int gsel = c & 3;
    const int ub = ubase + (c >> 2);
#pragma unroll
    for (int j = 0; j < 4; ++j) {
        float v = v4[j] + bias;
        float sig = 1.f / (1.f + __expf(-v));
        float act = (gsel == 2) ? (v > 0.f ? v : 0.f) : sig;
        float ig  = qbcast<0x00>(act);
        float fg  = qbcast<0x55>(act);
        float cin = qbcast<0xAA>(act);
        float og  = qbcast<0xFF>(act);
        int R = R0 + kq * 4 + j;
        float cp = cs[R * 33 + ub];
        float cn = fg * cp + ig * cin;
        float hn = og * (cn > 0.f ? cn : 0.f);
        if (gsel == 0) {
            cs[R * 33 + ub] = cn;
            hstp[(kq * 4 + j) * 40 + ub] = (_Float16)hn;
        }
    }
}

#define MFMA16(av, bv, acc) \
    acc = __builtin_amdgcn_mfma_f32_16x16x32_f16(av, bv, acc, 0, 0, 0)

// ---------------------------------------------------------------------------
// Persistent 2-layer LSTM — r18 = EXACT r11 (best verified, 4555us) plus:
//  (a) mapping-robust rowgroup barrier (r16 semantics: release fence ->
//      relaxed add/spin -> acquire fence; ~2 cache ops/superstep/block),
//  (b) L2 MFMA in 4 accumulator chains (dep depth 16 -> 8).
// Falsified & reverted: split-K (r12), flat pipeline (r13/14), Q1 fusion
// (r15/16 correctness), cs-in-regs (r17 spill).
// 256 blocks (1/CU) x 512 threads (8 waves, 2/SIMD); wave w owns one 16-col
// tile of both layers, full K, 200 AGPR-pinned weight regs; 9 pipelined
// regions/superstep, 1 barrier each; sc0 DMA; XCD-local rg mapping.
// ---------------------------------------------------------------------------
__global__ __launch_bounds__(512, 2) void lstm_persist(
    const float* __restrict__ x,
    const _Float16* __restrict__ Bp1, const float* __restrict__ pb1,
    const _Float16* __restrict__ Bp2, const float* __restrict__ pb2,
    const float* __restrict__ Wd, const float* __restrict__ bd,
    _Float16* __restrict__ h1b,   // [2][2048][512]
    _Float16* __restrict__ h2b,   // [2][2048][512]
    unsigned* __restrict__ bar,   // [16][32] rowgroup counters
    float* __restrict__ out)
{
    __shared__ _Float16 Q1[2][16 * QS];     // 32.5KB h1 chunks
    __shared__ _Float16 Q2[2][16 * QS];     // 32.5KB h2 chunks
    __shared__ _Float16 Xp[2][16][72];      // 4.5KB  x_t fp16
    __shared__ float    c1s[128 * 33];      // 16.5KB cell state L1
    __shared__ float    c2s[128 * 33];      // 16.5KB cell state L2
    __shared__ _Float16 hst[2][2][16][40];  // 5KB   [parity][layer][row][unit]

    const int tid = threadIdx.x;
    const int w = tid >> 6, lane = tid & 63;
    const int b = blockIdx.x;
    const int rg = 2 * (b & 7) + ((b >> 3) & 1);   // XCD-local rowgroup
    const int cg = b >> 4;
    const int r0 = rg * 128;
    const int c = lane & 15, kq = lane >> 4;

    for (int i = tid; i < 128 * 33; i += 512) { c1s[i] = 0.f; c2s[i] = 0.f; }
    for (int i = tid; i < 2 * 2 * 16 * 40; i += 512) (&hst[0][0][0][0])[i] = (_Float16)0.f;

    // ---- one-time: ALL weights -> AGPRs (200 regs/lane, "+a" pinned) ----
    const int ct = cg * 8 + w;
    f16x8 w1f[18], w2f[32];
#pragma unroll
    for (int kc = 0; kc < 18; ++kc)
        w1f[kc] = *(const f16x8*)(Bp1 + (((size_t)ct * KB1 + kc * 4 + kq) * 16 + c) * 8);
#pragma unroll
    for (int kc = 0; kc < 32; ++kc)
        w2f[kc] = *(const f16x8*)(Bp2 + (((size_t)ct * KB2 + kc * 4 + kq) * 16 + c) * 8);
#pragma unroll
    for (int kc = 0; kc < 18; ++kc) asm volatile("" : "+a"(w1f[kc]));
#pragma unroll
    for (int kc = 0; kc < 32; ++kc) asm volatile("" : "+a"(w2f[kc]));

    const float bias1 = pb1[ct * 16 + c];
    const float bias2 = pb2[ct * 16 + c];
    const int ub0 = w * 4;
    const int xrow = tid >> 5, xc2 = (tid & 31) * 2;

    for (int s = 0; s <= TT; ++s) {
        const int pr1 = (s + 1) & 1, pw1 = s & 1;
        const int pr2 = s & 1,       pw2 = (s + 1) & 1;
        const _Float16* h1r = h1b + (size_t)pr1 * 2048 * HH;
        const _Float16* h2r = h2b + (size_t)pr2 * 2048 * HH;
        _Float16* h1w = h1b + (size_t)pw1 * 2048 * HH;
        _Float16* h2w = h2b + (size_t)pw2 * 2048 * HH;
        const bool doL1 = (s < TT);
        const bool doL2 = (s >= 1);

        // ---- prologue: stage chunk 0 (DMA sc0) + x(0) ----
        {
#pragma unroll
            for (int i = 0; i < 2; ++i) {
                int r = w * 2 + i;
                gld_lds16_sc0(h1r + (size_t)(r0 + r) * HH + lane * 8, &Q1[0][r * QS]);
                gld_lds16_sc0(h2r + (size_t)(r0 + r) * HH + lane * 8, &Q2[0][r * QS]);
            }
            if (doL1) {
                float2 xv = *(const float2*)(x + ((size_t)(r0 + xrow) * TT + s) * FF + xc2);
                *(f16x2*)&Xp[0][xrow][xc2] = (f16x2){(_Float16)xv.x, (_Float16)xv.y};
            }
        }
        __syncthreads();

        // ---- pipelined regions: 1 barrier each ----
#pragma unroll
        for (int ch = 0; ch <= 8; ++ch) {
            const int par = ch & 1;

            // (1) DMA prefetch chunk ch+1 -> Q[par^1]
            if (ch <= 6) {
                const int gr = r0 + (ch + 1) * 16;
#pragma unroll
                for (int i = 0; i < 2; ++i) {
                    int r = w * 2 + i;
                    gld_lds16_sc0(h1r + (size_t)(gr + r) * HH + lane * 8, &Q1[par ^ 1][r * QS]);
                    gld_lds16_sc0(h2r + (size_t)(gr + r) * HH + lane * 8, &Q2[par ^ 1][r * QS]);
                }
            }
            float2 xnext{0.f, 0.f};
            const bool havex = (ch <= 6) && doL1;
            if (havex)
                xnext = *(const float2*)(x +
                    ((size_t)(r0 + (ch + 1) * 16 + xrow) * TT + s) * FF + xc2);

            // (2) hstore chunk ch-1 from hst[par^1] (256 threads, f16x4)
            if (ch >= 1 && tid < 256) {
                int layer = tid >> 7, r = (tid >> 3) & 15, cq = tid & 7;
                f16x4 hv = *(const f16x4*)&hst[par ^ 1][layer][r][cq * 4];
                _Float16* dst = (layer ? h2w : h1w)
                    + (size_t)(r0 + (ch - 1) * 16 + r) * HH + cg * 32 + cq * 4;
                *(f16x4*)dst = hv;
            }

            // (3) MFMA + epilogue for chunk ch
            if (ch <= 7) {
                const char* q1b = (const char*)&Q1[par][0] + c * (QS * 2);
                const char* q2b = (const char*)&Q2[par][0] + c * (QS * 2);
                if (doL1) {   // ---- L1: [h1 | x] @ [U1;W1], 2 acc chains ----
                    f32x4 a0{0.f, 0.f, 0.f, 0.f}, a1 = a0;
#pragma unroll
                    for (int kc = 0; kc < 8; ++kc) {
                        f16x8 av = *(const f16x8*)(q1b + kc * 64 + kq * 16);
                        MFMA16(av, w1f[kc], a0);
                    }
#pragma unroll
                    for (int kc = 8; kc < 16; ++kc) {
                        f16x8 av = *(const f16x8*)(q1b + kc * 64 + kq * 16);
                        MFMA16(av, w1f[kc], a1);
                    }
                    {
                        f16x8 av = *(const f16x8*)&Xp[par][c][kq * 8];
                        MFMA16(av, w1f[16], a0);
                        av = *(const f16x8*)&Xp[par][c][32 + kq * 8];
                        MFMA16(av, w1f[17], a1);
                    }
                    lstm_epi(a0 + a1, bias1, c1s, &hst[par][0][0][0], ch * 16, kq, c, ub0);
                }
                if (doL2) {   // ---- L2: [h2 | h1] @ [U2;W2], 4 acc chains ----
                    f32x4 b0{0.f, 0.f, 0.f, 0.f}, b1 = b0, b2 = b0, b3 = b0;
#pragma unroll
                    for (int kc = 0; kc < 8; ++kc) {
                        f16x8 av = *(const f16x8*)(q2b + kc * 64 + kq * 16);
                        MFMA16(av, w2f[kc], b0);
                    }
#pragma unroll
                    for (int kc = 8; kc < 16; ++kc) {
                        f16x8 av = *(const f16x8*)(q2b + kc * 64 + kq * 16);
                        MFMA16(av, w2f[kc], b1);
                    }
#pragma unroll
                    for (int kc = 0; kc < 8; ++kc) {
                        f16x8 av = *(const f16x8*)(q1b + kc * 64 + kq * 16);
                        MFMA16(av, w2f[16 + kc], b2);
                    }
#pragma unroll
                    for (int kc = 8; kc < 16; ++kc) {
                        f16x8 av = *(const f16x8*)(q1b + kc * 64 + kq * 16);
                        MFMA16(av, w2f[16 + kc], b3);
                    }
                    lstm_epi((b0 + b1) + (b2 + b3), bias2, c2s, &hst[par][1][0][0],
                             ch * 16, kq, c, ub0);
                }
            }

            // (4) x(ch+1) -> Xp[par^1]
            if (havex)
                *(f16x2*)&Xp[par ^ 1][xrow][xc2] =
                    (f16x2){(_Float16)xnext.x, (_Float16)xnext.y};

            __syncthreads();   // single barrier per region
        }

        // ---- rowgroup barrier: release fence -> relaxed add/spin -> acquire
        // fence. Mapping-robust (r16); relaxed polls avoid the r2 inv storm.
        if (tid == 0) {
            __threadfence();   // release: wbl2 pushes this block's h-lines to L3
            __hip_atomic_fetch_add(&bar[rg * 32], 1u,
                                   __ATOMIC_RELAXED, __HIP_MEMORY_SCOPE_AGENT);
            const unsigned target = 16u * (unsigned)(s + 1);
            while (__hip_atomic_load(&bar[rg * 32],
                                     __ATOMIC_RELAXED, __HIP_MEMORY_SCOPE_AGENT) < target)
                __builtin_amdgcn_s_sleep(2);
            __threadfence();   // acquire: inv drops stale L2 lines before next DMA
        }
        __syncthreads();
    }

    // ---- dense head: out = h2_127 @ Wd + bd (cg==0 blocks; 4 threads/row) ----
    if (cg == 0) {
        const _Float16* hf = h2b + (size_t)((TT + 1) & 1) * 2048 * HH;
        int row = tid >> 2, part = tid & 3;
        const _Float16* hr = hf + (size_t)(r0 + row) * HH + part * 128;
        const float* wd = Wd + part * 128;
        float ssum = 0.f;
#pragma unroll
        for (int u8 = 0; u8 < 16; ++u8) {
            f16x8 hv = *(const f16x8*)(hr + u8 * 8);
#pragma unroll
            for (int k = 0; k < 8; ++k) ssum += (float)hv[k] * wd[u8 * 8 + k];
        }
        ssum += __shfl_xor(ssum, 1);
        ssum += __shfl_xor(ssum, 2);
        if (part == 0) out[r0 + row] = ssum + bd[0];
    }
}

extern "C" void kernel_launch(void* const* d_in, const int* in_sizes, int n_in,
                              void* d_out, int out_size, void* d_ws, size_t ws_size,
                              hipStream_t stream)
{
    const float* x  = (const float*)d_in[0];
    const float* W1 = (const float*)d_in[1];
    const float* U1 = (const float*)d_in[2];
    const float* b1 = (const float*)d_in[3];
    const float* W2 = (const float*)d_in[4];
    const float* U2 = (const float*)d_in[5];
    const float* b2 = (const float*)d_in[6];
    const float* Wd = (const float*)d_in[7];
    const float* bd = (const float*)d_in[8];
    float* out = (float*)d_out;

    char* ws = (char*)d_ws;
    size_t off = 0;
    _Float16* Bp1 = (_Float16*)(ws + off); off += (size_t)K1 * GG * 2;
    _Float16* Bp2 = (_Float16*)(ws + off); off += (size_t)K2 * GG * 2;
    float*    pb1 = (float*)(ws + off);    off += (size_t)GG * 4;
    float*    pb2 = (float*)(ws + off);    off += (size_t)GG * 4;
    _Float16* h1b = (_Float16*)(ws + off); off += (size_t)2 * 2048 * HH * 2;
    _Float16* h2b = (_Float16*)(ws + off); off += (size_t)2 * 2048 * HH * 2;
    unsigned* bar = (unsigned*)(ws + off); off += 16 * 32 * 4;

    hipMemsetAsync(h1b, 0, (size_t)2 * 2048 * HH * 2, stream);
    hipMemsetAsync(h2b, 0, (size_t)2 * 2048 * HH * 2, stream);
    hipMemsetAsync(bar, 0, 16 * 32 * 4, stream);

    pack_weights<<<KB1, 256, 0, stream>>>(U1, W1, b1, KB1, HH, Bp1, pb1);
    pack_weights<<<KB2, 256, 0, stream>>>(U2, W2, b2, KB2, HH, Bp2, pb2);
    lstm_persist<<<NBLK, 512, 0, stream>>>(x, Bp1, pb1, Bp2, pb2, Wd, bd,
                                           h1b, h2b, bar, out);
}

// Round 19
// 7215.748 us; speedup vs baseline: 1.5026x; 1.1816x over previous
//
#include <hip/hip_runtime.h>

#define TT   128
#define FF   64
#define HH   512
#define GG   2048    // 4H
#define K1   576
#define K2   1024
#define KB1  72      // K1/8
#define KB2  128     // K2/8
#define NBLK 256
#define QS   520     // Q row stride in halves (1040B, 16B-aligned)

using f16x8 = __attribute__((ext_vector_type(8))) _Float16;
using f16x4 = __attribute__((ext_vector_type(4))) _Float16;
using f16x2 = __attribute__((ext_vector_type(2))) _Float16;
using f32x4 = __attribute__((ext_vector_type(4))) float;

// ---------------------------------------------------------------------------
// Coalesced repack (validated r9-r18): block kb stages 8 rows of [U;W] into
// LDS, writes dest-linear 16B chunks. Layout: element (ct,kb,c,j) at
// ((ct*K8+kb)*16+c)*8+j holds B[k=kb*8+j][col], col=(c&3)*512+ct*4+(c>>2).
// ---------------------------------------------------------------------------
__global__ void pack_weights(const float* __restrict__ U, const float* __restrict__ W,
                             const float* __restrict__ bias, int K8, int Kh,
                             _Float16* __restrict__ Bp, float* __restrict__ pb)
{
    __shared__ _Float16 T[8][GG];
    const int kb = blockIdx.x;
    const int tid = threadIdx.x;
    for (int i = tid; i < 8 * (GG / 4); i += 256) {
        int r = i / (GG / 4), c4 = (i % (GG / 4)) * 4;
        int k = kb * 8 + r;
        const float* src = (k < Kh) ? (U + (size_t)k * GG) : (W + (size_t)(k - Kh) * GG);
        float4 v = *(const float4*)(src + c4);
        T[r][c4 + 0] = (_Float16)v.x; T[r][c4 + 1] = (_Float16)v.y;
        T[r][c4 + 2] = (_Float16)v.z; T[r][c4 + 3] = (_Float16)v.w;
    }
    __syncthreads();
    for (int m = tid; m < 2048; m += 256) {
        int ct = m >> 4, c = m & 15;
        int col = (c & 3) * HH + ct * 4 + (c >> 2);
        f16x8 v;
#pragma unroll
        for (int j = 0; j < 8; ++j) v[j] = T[j][col];
        *(f16x8*)(Bp + (((size_t)ct * K8 + kb) * 16 + c) * 8) = v;
    }
    if (kb == 0)
        for (int p = tid; p < GG; p += 256) {
            int ct = p >> 4, c = p & 15;
            pb[p] = bias[(c & 3) * HH + ct * 4 + (c >> 2)];
        }
}

// DPP quad_perm broadcast (VALU). Validated r3-r18.
template <int CTRL>
__device__ __forceinline__ float qbcast(float v) {
    return __int_as_float(__builtin_amdgcn_mov_dpp(__float_as_int(v), CTRL, 0xF, 0xF, true));
}

// async global->LDS DMA, 16B/lane, sc0 (L1-bypass; L2 is coherence point). r9.
__device__ __forceinline__ void gld_lds16_sc0(const _Float16* g, _Float16* l) {
    __builtin_amdgcn_global_load_lds(
        (__attribute__((address_space(1))) const void*)g,
        (__attribute__((address_space(3))) void*)l, 16, 0, 1);
}

// ---------------------------------------------------------------------------
// Gate epilogue — r11 form (validated fast+correct): single-activation +
// DPP quad-broadcast; cell state in LDS stride 33 (conflict-free; r17 showed
// registers spill). C/D 16x16: col=lane&15, row=kq*4+j. hst stride 40.
// ---------------------------------------------------------------------------
__device__ __forceinline__ void lstm_epi(
    f32x4 v4, float bias, float* __restrict__ cs, _Float16* __restrict__ hstp,
    int R0, int kq, int c, int ubase)
{
    const int gsel = c & 3;
    const int ub = ubase + (c >> 2);
#pragma unroll
    for (int j = 0; j < 4; ++j) {
        float v = v4[j] + bias;
        float sig = 1.f / (1.f + __expf(-v));
        float act = (gsel == 2) ? (v > 0.f ? v : 0.f) : sig;
        float ig  = qbcast<0x00>(act);
        float fg  = qbcast<0x55>(act);
        float cin = qbcast<0xAA>(act);
        float og  = qbcast<0xFF>(act);
        int R = R0 + kq * 4 + j;
        float cp = cs[R * 33 + ub];
        float cn = fg * cp + ig * cin;
        float hn = og * (cn > 0.f ? cn : 0.f);
        if (gsel == 0) {
            cs[R * 33 + ub] = cn;
            hstp[(kq * 4 + j) * 40 + ub] = (_Float16)hn;
        }
    }
}

#define MFMA16(av, bv, acc) \
    acc = __builtin_amdgcn_mfma_f32_16x16x32_f16(av, bv, acc, 0, 0, 0)

// ---------------------------------------------------------------------------
// Persistent 2-layer LSTM — r19 = EXACT r11 (best verified, 4555us, RELAXED
// barrier — r18 proved the fenced variant costs 4ms via per-superstep
// buffer_inv L2 wipes) + two zero-risk micro-levers:
//  (a) L2 MFMA in 4 accumulator chains (r18-validated numerics, dep 16->8)
//  (b) s_setprio(1) around the MFMA+epilogue phase (T5: our pipelined
//      regions have wave role-diversity -> scheduler can favor MFMA waves)
// 256 blocks (1/CU) x 512 threads (8 waves, 2/SIMD); wave w owns one 16-col
// tile of both layers, full K, 200 AGPR-pinned weight regs; 9 pipelined
// regions/superstep, 1 barrier each; sc0 DMA; XCD-local rg mapping (r8).
// ---------------------------------------------------------------------------
__global__ __launch_bounds__(512, 2) void lstm_persist(
    const float* __restrict__ x,
    const _Float16* __restrict__ Bp1, const float* __restrict__ pb1,
    const _Float16* __restrict__ Bp2, const float* __restrict__ pb2,
    const float* __restrict__ Wd, const float* __restrict__ bd,
    _Float16* __restrict__ h1b,   // [2][2048][512]
    _Float16* __restrict__ h2b,   // [2][2048][512]
    unsigned* __restrict__ bar,   // [16][32] rowgroup counters
    float* __restrict__ out)
{
    __shared__ _Float16 Q1[2][16 * QS];     // 32.5KB h1 chunks
    __shared__ _Float16 Q2[2][16 * QS];     // 32.5KB h2 chunks
    __shared__ _Float16 Xp[2][16][72];      // 4.5KB  x_t fp16
    __shared__ float    c1s[128 * 33];      // 16.5KB cell state L1
    __shared__ float    c2s[128 * 33];      // 16.5KB cell state L2
    __shared__ _Float16 hst[2][2][16][40];  // 5KB   [parity][layer][row][unit]

    const int tid = threadIdx.x;
    const int w = tid >> 6, lane = tid & 63;
    const int b = blockIdx.x;
    const int rg = 2 * (b & 7) + ((b >> 3) & 1);   // XCD-local rowgroup
    const int cg = b >> 4;
    const int r0 = rg * 128;
    const int c = lane & 15, kq = lane >> 4;

    for (int i = tid; i < 128 * 33; i += 512) { c1s[i] = 0.f; c2s[i] = 0.f; }
    for (int i = tid; i < 2 * 2 * 16 * 40; i += 512) (&hst[0][0][0][0])[i] = (_Float16)0.f;

    // ---- one-time: ALL weights -> AGPRs (200 regs/lane, "+a" pinned) ----
    const int ct = cg * 8 + w;
    f16x8 w1f[18], w2f[32];
#pragma unroll
    for (int kc = 0; kc < 18; ++kc)
        w1f[kc] = *(const f16x8*)(Bp1 + (((size_t)ct * KB1 + kc * 4 + kq) * 16 + c) * 8);
#pragma unroll
    for (int kc = 0; kc < 32; ++kc)
        w2f[kc] = *(const f16x8*)(Bp2 + (((size_t)ct * KB2 + kc * 4 + kq) * 16 + c) * 8);
#pragma unroll
    for (int kc = 0; kc < 18; ++kc) asm volatile("" : "+a"(w1f[kc]));
#pragma unroll
    for (int kc = 0; kc < 32; ++kc) asm volatile("" : "+a"(w2f[kc]));

    const float bias1 = pb1[ct * 16 + c];
    const float bias2 = pb2[ct * 16 + c];
    const int ub0 = w * 4;
    const int xrow = tid >> 5, xc2 = (tid & 31) * 2;

    for (int s = 0; s <= TT; ++s) {
        const int pr1 = (s + 1) & 1, pw1 = s & 1;
        const int pr2 = s & 1,       pw2 = (s + 1) & 1;
        const _Float16* h1r = h1b + (size_t)pr1 * 2048 * HH;
        const _Float16* h2r = h2b + (size_t)pr2 * 2048 * HH;
        _Float16* h1w = h1b + (size_t)pw1 * 2048 * HH;
        _Float16* h2w = h2b + (size_t)pw2 * 2048 * HH;
        const bool doL1 = (s < TT);
        const bool doL2 = (s >= 1);

        // ---- prologue: stage chunk 0 (DMA sc0) + x(0) ----
        {
#pragma unroll
            for (int i = 0; i < 2; ++i) {
                int r = w * 2 + i;
                gld_lds16_sc0(h1r + (size_t)(r0 + r) * HH + lane * 8, &Q1[0][r * QS]);
                gld_lds16_sc0(h2r + (size_t)(r0 + r) * HH + lane * 8, &Q2[0][r * QS]);
            }
            if (doL1) {
                float2 xv = *(const float2*)(x + ((size_t)(r0 + xrow) * TT + s) * FF + xc2);
                *(f16x2*)&Xp[0][xrow][xc2] = (f16x2){(_Float16)xv.x, (_Float16)xv.y};
            }
        }
        __syncthreads();

        // ---- pipelined regions: 1 barrier each ----
#pragma unroll
        for (int ch = 0; ch <= 8; ++ch) {
            const int par = ch & 1;

            // (1) DMA prefetch chunk ch+1 -> Q[par^1]
            if (ch <= 6) {
                const int gr = r0 + (ch + 1) * 16;
#pragma unroll
                for (int i = 0; i < 2; ++i) {
                    int r = w * 2 + i;
                    gld_lds16_sc0(h1r + (size_t)(gr + r) * HH + lane * 8, &Q1[par ^ 1][r * QS]);
                    gld_lds16_sc0(h2r + (size_t)(gr + r) * HH + lane * 8, &Q2[par ^ 1][r * QS]);
                }
            }
            float2 xnext{0.f, 0.f};
            const bool havex = (ch <= 6) && doL1;
            if (havex)
                xnext = *(const float2*)(x +
                    ((size_t)(r0 + (ch + 1) * 16 + xrow) * TT + s) * FF + xc2);

            // (2) hstore chunk ch-1 from hst[par^1] (256 threads, f16x4)
            if (ch >= 1 && tid < 256) {
                int layer = tid >> 7, r = (tid >> 3) & 15, cq = tid & 7;
                f16x4 hv = *(const f16x4*)&hst[par ^ 1][layer][r][cq * 4];
                _Float16* dst = (layer ? h2w : h1w)
                    + (size_t)(r0 + (ch - 1) * 16 + r) * HH + cg * 32 + cq * 4;
                *(f16x4*)dst = hv;
            }

            // (3) MFMA + epilogue for chunk ch — setprio(1) while in the
            // matrix/epilogue phase (waves here race waves doing DMA/hstore)
            if (ch <= 7) {
                __builtin_amdgcn_s_setprio(1);
                const char* q1b = (const char*)&Q1[par][0] + c * (QS * 2);
                const char* q2b = (const char*)&Q2[par][0] + c * (QS * 2);
                if (doL1) {   // ---- L1: [h1 | x] @ [U1;W1], 2 acc chains ----
                    f32x4 a0{0.f, 0.f, 0.f, 0.f}, a1 = a0;
#pragma unroll
                    for (int kc = 0; kc < 8; ++kc) {
                        f16x8 av = *(const f16x8*)(q1b + kc * 64 + kq * 16);
                        MFMA16(av, w1f[kc], a0);
                    }
#pragma unroll
                    for (int kc = 8; kc < 16; ++kc) {
                        f16x8 av = *(const f16x8*)(q1b + kc * 64 + kq * 16);
                        MFMA16(av, w1f[kc], a1);
                    }
                    {
                        f16x8 av = *(const f16x8*)&Xp[par][c][kq * 8];
                        MFMA16(av, w1f[16], a0);
                        av = *(const f16x8*)&Xp[par][c][32 + kq * 8];
                        MFMA16(av, w1f[17], a1);
                    }
                    lstm_epi(a0 + a1, bias1, c1s, &hst[par][0][0][0], ch * 16, kq, c, ub0);
                }
                if (doL2) {   // ---- L2: [h2 | h1] @ [U2;W2], 4 acc chains ----
                    f32x4 b0{0.f, 0.f, 0.f, 0.f}, b1 = b0, b2 = b0, b3 = b0;
#pragma unroll
                    for (int kc = 0; kc < 8; ++kc) {
                        f16x8 av = *(const f16x8*)(q2b + kc * 64 + kq * 16);
                        MFMA16(av, w2f[kc], b0);
                    }
#pragma unroll
                    for (int kc = 8; kc < 16; ++kc) {
                        f16x8 av = *(const f16x8*)(q2b + kc * 64 + kq * 16);
                        MFMA16(av, w2f[kc], b1);
                    }
#pragma unroll
                    for (int kc = 0; kc < 8; ++kc) {
                        f16x8 av = *(const f16x8*)(q1b + kc * 64 + kq * 16);
                        MFMA16(av, w2f[16 + kc], b2);
                    }
#pragma unroll
                    for (int kc = 8; kc < 16; ++kc) {
                        f16x8 av = *(const f16x8*)(q1b + kc * 64 + kq * 16);
                        MFMA16(av, w2f[16 + kc], b3);
                    }
                    lstm_epi((b0 + b1) + (b2 + b3), bias2, c2s, &hst[par][1][0][0],
                             ch * 16, kq, c, ub0);
                }
                __builtin_amdgcn_s_setprio(0);
            }

            // (4) x(ch+1) -> Xp[par^1]
            if (havex)
                *(f16x2*)&Xp[par ^ 1][xrow][xc2] =
                    (f16x2){(_Float16)xnext.x, (_Float16)xnext.y};

            __syncthreads();   // single barrier per region
        }

        // ---- rowgroup barrier, RELAXED (r9-validated; r18 proved fences
        // cost 4ms via L2 wipes). Same-XCD L2 is the coherence point. ----
        if (tid == 0) {
            __hip_atomic_fetch_add(&bar[rg * 32], 1u,
                                   __ATOMIC_RELAXED, __HIP_MEMORY_SCOPE_AGENT);
            const unsigned target = 16u * (unsigned)(s + 1);
            while (__hip_atomic_load(&bar[rg * 32],
                                     __ATOMIC_RELAXED, __HIP_MEMORY_SCOPE_AGENT) < target)
                __builtin_amdgcn_s_sleep(2);
        }
        __syncthreads();
    }

    // ---- dense head: out = h2_127 @ Wd + bd (cg==0 blocks; 4 threads/row) ----
    if (cg == 0) {
        const _Float16* hf = h2b + (size_t)((TT + 1) & 1) * 2048 * HH;
        int row = tid >> 2, part = tid & 3;
        const _Float16* hr = hf + (size_t)(r0 + row) * HH + part * 128;
        const float* wd = Wd + part * 128;
        float ssum = 0.f;
#pragma unroll
        for (int u8 = 0; u8 < 16; ++u8) {
            f16x8 hv = *(const f16x8*)(hr + u8 * 8);
#pragma unroll
            for (int k = 0; k < 8; ++k) ssum += (float)hv[k] * wd[u8 * 8 + k];
        }
        ssum += __shfl_xor(ssum, 1);
        ssum += __shfl_xor(ssum, 2);
        if (part == 0) out[r0 + row] = ssum + bd[0];
    }
}

extern "C" void kernel_launch(void* const* d_in, const int* in_sizes, int n_in,
                              void* d_out, int out_size, void* d_ws, size_t ws_size,
                              hipStream_t stream)
{
    const float* x  = (const float*)d_in[0];
    const float* W1 = (const float*)d_in[1];
    const float* U1 = (const float*)d_in[2];
    const float* b1 = (const float*)d_in[3];
    const float* W2 = (const float*)d_in[4];
    const float* U2 = (const float*)d_in[5];
    const float* b2 = (const float*)d_in[6];
    const float* Wd = (const float*)d_in[7];
    const float* bd = (const float*)d_in[8];
    float* out = (float*)d_out;

    char* ws = (char*)d_ws;
    size_t off = 0;
    _Float16* Bp1 = (_Float16*)(ws + off); off += (size_t)K1 * GG * 2;
    _Float16* Bp2 = (_Float16*)(ws + off); off += (size_t)K2 * GG * 2;
    float*    pb1 = (float*)(ws + off);    off += (size_t)GG * 4;
    float*    pb2 = (float*)(ws + off);    off += (size_t)GG * 4;
    _Float16* h1b = (_Float16*)(ws + off); off += (size_t)2 * 2048 * HH * 2;
    _Float16* h2b = (_Float16*)(ws + off); off += (size_t)2 * 2048 * HH * 2;
    unsigned* bar = (unsigned*)(ws + off); off += 16 * 32 * 4;

    hipMemsetAsync(h1b, 0, (size_t)2 * 2048 * HH * 2, stream);
    hipMemsetAsync(h2b, 0, (size_t)2 * 2048 * HH * 2, stream);
    hipMemsetAsync(bar, 0, 16 * 32 * 4, stream);

    pack_weights<<<KB1, 256, 0, stream>>>(U1, W1, b1, KB1, HH, Bp1, pb1);
    pack_weights<<<KB2, 256, 0, stream>>>(U2, W2, b2, KB2, HH, Bp2, pb2);
    lstm_persist<<<NBLK, 512, 0, stream>>>(x, Bp1, pb1, Bp2, pb2, Wd, bd,
                                           h1b, h2b, bar, out);
}